// Round 14
// baseline (265.387 us; speedup 1.0000x reference)
//
#include <hip/hip_runtime.h>
#include <hip/hip_bf16.h>

#define BB 4
#define NN 32
#define MM 64
#define KK 16
#define KK1 17
#define PP 128
#define CC 2

typedef unsigned short ushort_t;
typedef unsigned int uint32;
typedef __attribute__((ext_vector_type(8))) short bhalf8;
typedef __attribute__((ext_vector_type(4))) float floatx4;

#define TK  2.885390082f   // 2*log2(e): tanh(x) = 1 - 2/(exp2(x*TK)+1)
#define L2E 1.44269504f

// 5-inst tanh: mul/fma upstream, v_exp, v_add, v_rcp, v_fma.
__device__ __forceinline__ float tanh_pre(float xs) {   // xs = x*TK already
    float e = __builtin_amdgcn_exp2f(xs);
    return fmaf(-2.0f, __builtin_amdgcn_rcpf(e + 1.0f), 1.0f);
}

__device__ __forceinline__ ushort_t f2b(float f) {
    uint32 u = __float_as_uint(f);
    return (ushort_t)((u + 0x8000u) >> 16);
}
__device__ __forceinline__ float b2f(ushort_t h) {
    return __uint_as_float(((uint32)h) << 16);
}

// u,w are PRE-SCALED by TK at generation (attn u-emit / attn prologue w_ws)
__device__ __forceinline__ bhalf8 tanh_uw(bhalf8 u, bhalf8 w) {
    bhalf8 h;
    #pragma unroll
    for (int j = 0; j < 8; ++j)
        h[j] = (short)f2b(tanh_pre(b2f((ushort_t)u[j]) + b2f((ushort_t)w[j])));
    return h;
}

// ---------------------------------------------------------------------------
// Prep (SHRUNK, R14): only the attn-gating weights W0a/W1a (6144 elements,
// 24 blocks, ~1-2 us). The transport-only conversions (W1t/W2t/S0t/S1t/w_ws,
// 196K elements) moved into attn's prologue — they were serializing ~4-6 us
// on the critical path for data attn never reads. transport launches after
// attn, so all its inputs are complete. Race-free by construction.
// ---------------------------------------------------------------------------
__global__ void prep_kernel(const float* __restrict__ aw0, const float* __restrict__ aw1,
                            ushort_t* __restrict__ W0a, ushort_t* __restrict__ W1a) {
    int i = blockIdx.x * 256 + threadIdx.x;
    if (i < 2048) {
        int nn = i >> 5, k = i & 31;
        W0a[i] = (k < 6) ? f2b(aw0[k * 64 + nn]) : (ushort_t)0;
    } else if (i < 6144) {
        int j = i - 2048; int nn = j >> 6, k = j & 63;
        W1a[j] = f2b(aw1[k * 64 + nn]);
    }
}

// ---------------------------------------------------------------------------
// Kernel A (MFMA attn): R4 128-thr/2-wave structure + merged 2-round softmax.
// R14: + distributed prep prologue (<=1 global conversion per thread,
// overlapped with the fill-phase loads). sH0 ALIASES sA0. LDS 19.5 KB ->
// 8 blocks/CU. Emits u_ws (PRE-SCALED by TK).
// ---------------------------------------------------------------------------
#define AH0S 72

__global__ __launch_bounds__(128, 4) void attn_kernel(
    const float* __restrict__ phase, const float* __restrict__ posc,
    const float* __restrict__ sigma, const float* __restrict__ velc,
    const ushort_t* __restrict__ W0a, const ushort_t* __restrict__ W1a,
    const float* __restrict__ ab0, const float* __restrict__ ab1,
    const float* __restrict__ aw2, const float* __restrict__ ab2,
    const float* __restrict__ tw0, ushort_t* __restrict__ u_ws,
    // prologue inputs/outputs (transport weights; attn never reads these)
    const float* __restrict__ tw1, const float* __restrict__ tw2,
    const float* __restrict__ sw0, const float* __restrict__ sw1,
    const float* __restrict__ tb0, const float* __restrict__ bcoord,
    ushort_t* __restrict__ W1t, ushort_t* __restrict__ W2t,
    ushort_t* __restrict__ S0t, ushort_t* __restrict__ S1t,
    ushort_t* __restrict__ w_ws)
{
    __shared__ __align__(16) ushort_t sAH[128 * AH0S];
    __shared__ float sPL[128];
    __shared__ float sLG[128];
    __shared__ float s_red[8];

    const int tid = threadIdx.x;
    const int wave = tid >> 6;
    const int lane = tid & 63;
    const int lrow = lane & 15;
    const int lkg  = lane >> 4;

    const int blk = blockIdx.x;
    const int b = blk / (NN * KK1);
    const int rem = blk % (NN * KK1);
    const int n = rem / KK1;
    const int k = rem % KK1;

    // ---- distributed prep prologue (no LDS, no barrier; 196608 < 278528) ----
    {
        const int gid = blk * 128 + tid;
        if (gid < 65536) {
            int nn = gid >> 8, kk = gid & 255;
            W1t[gid] = f2b(tw1[kk * 256 + nn]);
        } else if (gid < 98304) {
            int j = gid - 65536; int nn = j >> 8, kk = j & 255;
            W2t[j] = f2b(tw2[kk * 128 + nn]);
        } else if (gid < 114688) {
            S0t[gid - 98304] = f2b(sw0[gid - 98304]);
        } else if (gid < 131072) {
            S1t[gid - 114688] = f2b(sw1[gid - 114688]);
        } else if (gid < 196608) {
            int j = gid - 131072;
            int m = j >> 8, c = j & 255;   // m = b*64 + mm
            float v = bcoord[m * 4 + 0] * tw0[4 * 256 + c]
                    + bcoord[m * 4 + 1] * tw0[5 * 256 + c]
                    + bcoord[m * 4 + 2] * tw0[6 * 256 + c]
                    + bcoord[m * 4 + 3] * tw0[7 * 256 + c]
                    + tb0[c];
            w_ws[j] = f2b(v * TK);
        }
    }

    float x0, x1, va0, va1;
    {
        const int p = tid;
        x0 = phase[(b * NN + n) * 4 + 0];
        x1 = phase[(b * NN + n) * 4 + 1];
        if (k == 0) { va0 = phase[(b * NN + n) * 4 + 2]; va1 = phase[(b * NN + n) * 4 + 3]; }
        else { va0 = velc[(b * KK + (k - 1)) * 2 + 0]; va1 = velc[(b * KK + (k - 1)) * 2 + 1]; }
        const float inv = rsqrtf(va0 * va0 + va1 * va1 + 1e-16f);
        const float ag0 = va0 * inv, ag1 = va1 * inv;
        const float px = posc[(b * PP + p) * 2 + 0];
        const float py = posc[(b * PP + p) * 2 + 1];
        const float r0 = x0 - px, r1 = x1 - py;
        const float rd = sqrtf(r0 * r0 + r1 * r1 + 1e-16f);
        const float pl = r0 * ag0 + r1 * ag1;
        const float al = pl * __builtin_amdgcn_rcpf(rd + 1e-8f);
        sPL[p] = pl;
        bhalf8 f0;
        f0[0] = (short)f2b(x0); f0[1] = (short)f2b(x1);
        f0[2] = (short)f2b(va0); f0[3] = (short)f2b(va1);
        f0[4] = (short)f2b(al); f0[5] = (short)f2b(pl);
        f0[6] = 0; f0[7] = 0;
        bhalf8 z = {0, 0, 0, 0, 0, 0, 0, 0};
        *(bhalf8*)&sAH[p * 32 + 0] = f0;
        *(bhalf8*)&sAH[p * 32 + 8] = z;   // zero pad cols (NaN-safe 0*A)
        *(bhalf8*)&sAH[p * 32 + 16] = z;
        *(bhalf8*)&sAH[p * 32 + 24] = z;
    }
    __syncthreads();

    // ---- L1: h0 = tanh(A0 @ W0a + ab0) -> sH0 (aliases sA0) ----
    {
        float b0v[4];
        #pragma unroll
        for (int j = 0; j < 4; ++j) b0v[j] = ab0[j * 16 + lrow] * TK;
        bhalf8 a[4];
        #pragma unroll
        for (int mtl = 0; mtl < 4; ++mtl)
            a[mtl] = *(const bhalf8*)&sAH[(wave * 64 + mtl * 16 + lrow) * 32 + lkg * 8];
        __syncthreads();   // all waves hold A-frags in regs; sA0 region now dead
        #pragma unroll
        for (int j = 0; j < 4; ++j) {
            bhalf8 bf = *(const bhalf8*)(W0a + (j * 16 + lrow) * 32 + lkg * 8);
            #pragma unroll
            for (int mtl = 0; mtl < 4; ++mtl) {
                floatx4 c = {0.f, 0.f, 0.f, 0.f};
                c = __builtin_amdgcn_mfma_f32_16x16x32_bf16(a[mtl], bf, c, 0, 0, 0);
                #pragma unroll
                for (int q = 0; q < 4; ++q) {
                    int row = wave * 64 + mtl * 16 + lkg * 4 + q;
                    sAH[row * AH0S + j * 16 + lrow] = f2b(tanh_pre(fmaf(c[q], TK, b0v[j])));
                }
            }
        }
    }
    __syncthreads();

    // ---- L2 + logit ----
    {
        float b1v[4], w2v[4];
        #pragma unroll
        for (int j = 0; j < 4; ++j) { b1v[j] = ab1[j * 16 + lrow] * TK; w2v[j] = aw2[j * 16 + lrow]; }
        bhalf8 a0[4], a1[4];
        #pragma unroll
        for (int mtl = 0; mtl < 4; ++mtl) {
            int base = (wave * 64 + mtl * 16 + lrow) * AH0S;
            a0[mtl] = *(const bhalf8*)&sAH[base + lkg * 8];
            a1[mtl] = *(const bhalf8*)&sAH[base + 32 + lkg * 8];
        }
        float s[4][4];
        #pragma unroll
        for (int mtl = 0; mtl < 4; ++mtl)
            #pragma unroll
            for (int q = 0; q < 4; ++q) s[mtl][q] = 0.0f;
        #pragma unroll
        for (int j = 0; j < 4; ++j) {
            bhalf8 bf0 = *(const bhalf8*)(W1a + (j * 16 + lrow) * 64 + lkg * 8);
            bhalf8 bf1 = *(const bhalf8*)(W1a + (j * 16 + lrow) * 64 + 32 + lkg * 8);
            #pragma unroll
            for (int mtl = 0; mtl < 4; ++mtl) {
                floatx4 c = {0.f, 0.f, 0.f, 0.f};
                c = __builtin_amdgcn_mfma_f32_16x16x32_bf16(a0[mtl], bf0, c, 0, 0, 0);
                c = __builtin_amdgcn_mfma_f32_16x16x32_bf16(a1[mtl], bf1, c, 0, 0, 0);
                #pragma unroll
                for (int q = 0; q < 4; ++q)
                    s[mtl][q] += tanh_pre(fmaf(c[q], TK, b1v[j])) * w2v[j];
            }
        }
        #pragma unroll
        for (int mask = 1; mask <= 8; mask <<= 1)
            #pragma unroll
            for (int mtl = 0; mtl < 4; ++mtl)
                #pragma unroll
                for (int q = 0; q < 4; ++q)
                    s[mtl][q] += __shfl_xor(s[mtl][q], mask, 64);
        if (lrow == 0) {
            #pragma unroll
            for (int mtl = 0; mtl < 4; ++mtl)
                #pragma unroll
                for (int q = 0; q < 4; ++q)
                    sLG[wave * 64 + mtl * 16 + lkg * 4 + q] = s[mtl][q];
        }
    }
    __syncthreads();

    // ---- softmax (2 rounds, merged sv/s0/s1) + coeff -> u emit ----
    {
        const int p = tid;
        const float ml = (sPL[p] > 0.0f) ? (sLG[p] + ab2[0]) : -1e30f;
        const int wid = wave;
        float mv = ml;
        for (int o = 32; o > 0; o >>= 1) mv = fmaxf(mv, __shfl_xor(mv, o, 64));
        if (lane == 0) s_red[wid] = mv;
        __syncthreads();
        mv = fmaxf(s_red[0], s_red[1]);

        const float ew = __expf(ml - mv);
        float sv = ew;
        float s0 = ew * sigma[(b * PP + p) * 2 + 0];
        float s1 = ew * sigma[(b * PP + p) * 2 + 1];
        for (int o = 32; o > 0; o >>= 1) {
            sv += __shfl_xor(sv, o, 64);
            s0 += __shfl_xor(s0, o, 64);
            s1 += __shfl_xor(s1, o, 64);
        }
        if (lane == 0) { s_red[2 + wid] = sv; s_red[4 + wid] = s0; s_red[6 + wid] = s1; }
        __syncthreads();

        const float rsv = __builtin_amdgcn_rcpf(s_red[2] + s_red[3]);
        const float cc0 = __expf(-(s_red[4] + s_red[5]) * rsv);
        const float cc1 = __expf(-(s_red[6] + s_red[7]) * rsv);
        const float x0k = x0 * TK, x1k = x1 * TK;
        const float va0k = va0 * TK, va1k = va1 * TK;
        const float cc0k = cc0 * TK, cc1k = cc1 * TK;
        const int ubase = ((b * NN + n) * KK1 + k) * 256;
        for (int cc = tid; cc < 256; cc += 128) {
            float uv = x0k * tw0[cc] + x1k * tw0[256 + cc]
                     + va0k * tw0[512 + cc] + va1k * tw0[768 + cc]
                     + cc0k * tw0[2048 + cc] + cc1k * tw0[2304 + cc];
            u_ws[ubase + cc] = f2b(uv);
        }
    }
}

// ---------------------------------------------------------------------------
// Kernel B: MFMA transport. Byte-exact R10 structure (session best: 151 us).
// Closed levers (measured): LDS 40/32/28/22 KB (occ never moved);
// launch_bounds(256,5) (spill > occ gain, twice); accum restructures (R4 won
// via spill removal); bank conflicts (R12: counter -31%, timing neutral ->
// off the critical path at 4 blocks/CU).
// Remaining structure: barrier-serialized 9-phase chain, register-capped
// 4 blocks/CU, MfmaUtil 13% / VALUBusy 30% / HBM 0.6% -> latency regime.
//  - H0A FULL-K (34x264), filled once, ALL loads issued up-front.
//  - L1 col-halved: pass p computes col-tiles {2p,2p+1}, c1h[2][3]=24 accum.
//  - half-K compact H1A (34x136); W2t index ks*64 + p*32 + lkg*8.
//  - gv/nv in REGISTERS (writer thread == reader thread, lkg==0).
// Regions (u16 idx), lifetimes:
//   [0,8976)      H0A full (fill .. L1 pass1 reads; garbage rows to 12664)
//   [0,5128)      GTS (pads zeroed after H0A death; L2 epi .. resv2)
//   [5128,5640)   A2S (resvs .. resv2)
//   [8976,13600)  H1A half (pass epi .. L2 phase) -> AS2 (resvs .. sw0)
//                 -> A3 head (resv2 .. green)
//   [13600,14144) AS (start .. resvs)
//   floats: BBW u16 14144..14148, RED u16 14148..14156
// ---------------------------------------------------------------------------
#define H0S  264
#define H1S  136
#define GTSs 40
#define AS2S 136

#define U_H0A  0
#define U_GTS  0
#define U_A2S  5128
#define U_H1A  8976
#define U_AS2  8976
#define U_A3   8976
#define U_AS   13600
#define F_BBW  7072     // float idx -> u16 14144..14148
#define F_RED  7074     // float idx -> u16 14148..14156

__global__ __launch_bounds__(256, 4) void transport_kernel(
    const float* __restrict__ boundary, const float* __restrict__ bweights,
    const float* __restrict__ vweights, const float* __restrict__ scat,
    const float* __restrict__ selfscat,
    const ushort_t* __restrict__ W1t, const ushort_t* __restrict__ W2t,
    const ushort_t* __restrict__ S0t, const ushort_t* __restrict__ S1t,
    const float* __restrict__ tb1, const float* __restrict__ tb2,
    const float* __restrict__ sb0, const float* __restrict__ sb1,
    const float* __restrict__ outw,
    const ushort_t* __restrict__ u_ws, const ushort_t* __restrict__ w_ws,
    float* __restrict__ out)
{
    __shared__ __align__(16) ushort_t smem[14160];   // 28320 B
    float* smf = (float*)smem;

    const int tid = threadIdx.x;
    const int wave = tid >> 6;
    const int lane = tid & 63;
    const int lrow = lane & 15;
    const int lkg  = lane >> 4;

    const int blk = blockIdx.x;
    const int b  = blk >> 10;
    const int n  = (blk >> 5) & 31;
    const int mg = blk & 31;
    const int m0 = mg * 2;
    const int bn = b * NN + n;

    if (tid < 2)
        smf[F_BBW + tid] = boundary[b * MM + m0 + tid] * bweights[b * MM + m0 + tid];

    // ---- AS build ----
    for (int idx = tid; idx < 17 * 32; idx += 256) {
        int i = idx >> 5, c = idx & 31;
        float val = 0.0f;
        if (c < 16) {
            float vw = vweights[b * KK + c];
            val = (i < 16) ? (1.0f - selfscat[(b * KK + i) * KK + c]) * vw
                           : (1.0f - scat[bn * KK + c]) * vw;
        }
        smem[U_AS + idx] = f2b(val);
    }

    // ---- h0 fill, full-K, single phase. Loads issued up-front. ----
    {
        const int r0  = tid >> 5;        // 0..7
        const int oct = tid & 31;        // 0..31
        const int co  = oct * 8;
        const int rC  = 16 + r0;
        const int mlC = (rC >= 17) ? 1 : 0;
        const int kC  = rC - 17 * mlC;
        // only two distinct w rows (ml = 0/1): load once each
        const bhalf8 wml0 = *(const bhalf8*)(w_ws + (b * MM + m0 + 0) * 256 + co);
        const bhalf8 wml1 = *(const bhalf8*)(w_ws + (b * MM + m0 + 1) * 256 + co);
        const bhalf8 uA = *(const bhalf8*)(u_ws + (bn * KK1 + r0) * 256 + co);
        const bhalf8 uB = *(const bhalf8*)(u_ws + (bn * KK1 + 8 + r0) * 256 + co);
        const bhalf8 uC = *(const bhalf8*)(u_ws + (bn * KK1 + kC) * 256 + co);
        const bhalf8 uD = *(const bhalf8*)(u_ws + (bn * KK1 + 7 + r0) * 256 + co);
        bhalf8 uE;
        if (r0 < 2)
            uE = *(const bhalf8*)(u_ws + (bn * KK1 + 15 + r0) * 256 + co);
        *(bhalf8*)&smem[U_H0A + r0 * H0S + co]        = tanh_uw(uA, wml0);
        *(bhalf8*)&smem[U_H0A + (8 + r0) * H0S + co]  = tanh_uw(uB, wml0);
        *(bhalf8*)&smem[U_H0A + rC * H0S + co]        = tanh_uw(uC, mlC ? wml1 : wml0);
        *(bhalf8*)&smem[U_H0A + (24 + r0) * H0S + co] = tanh_uw(uD, wml1);
        if (r0 < 2)
            *(bhalf8*)&smem[U_H0A + (32 + r0) * H0S + co] = tanh_uw(uE, wml1);
    }
    __syncthreads();

    // ---- L1 col-half passes interleaved with L2 k-half phases ----
    floatx4 c2[2][3];
    #pragma unroll
    for (int j = 0; j < 2; ++j)
        #pragma unroll
        for (int mt = 0; mt < 3; ++mt) c2[j][mt] = (floatx4){0.f, 0.f, 0.f, 0.f};

    #pragma unroll
    for (int p = 0; p < 2; ++p) {
        // L1 pass p: cols {4*wave+2p, 4*wave+2p+1}, full K=256
        floatx4 c1h[2][3];
        #pragma unroll
        for (int j = 0; j < 2; ++j)
            #pragma unroll
            for (int mt = 0; mt < 3; ++mt) c1h[j][mt] = (floatx4){0.f, 0.f, 0.f, 0.f};
        #pragma unroll
        for (int ksl = 0; ksl < 8; ++ksl) {
            bhalf8 a[3];
            #pragma unroll
            for (int mt = 0; mt < 3; ++mt)
                a[mt] = *(const bhalf8*)&smem[U_H0A + (mt * 16 + lrow) * H0S + ksl * 32 + lkg * 8];
            #pragma unroll
            for (int jj = 0; jj < 2; ++jj) {
                bhalf8 bf = *(const bhalf8*)(W1t + ((4 * wave + 2 * p + jj) * 16 + lrow) * 256
                                             + ksl * 32 + lkg * 8);
                #pragma unroll
                for (int mt = 0; mt < 3; ++mt)
                    c1h[jj][mt] = __builtin_amdgcn_mfma_f32_16x16x32_bf16(a[mt], bf, c1h[jj][mt], 0, 0, 0);
            }
        }
        // epilogue -> compact H1A half (col = wave*32 + jj*16 + lrow)
        #pragma unroll
        for (int jj = 0; jj < 2; ++jj) {
            const float bb = tb1[(4 * wave + 2 * p + jj) * 16 + lrow] * TK;
            #pragma unroll
            for (int mt = 0; mt < 3; ++mt)
                #pragma unroll
                for (int q = 0; q < 4; ++q) {
                    const int row = mt * 16 + lkg * 4 + q;
                    if (row < 34)
                        smem[U_H1A + row * H1S + wave * 32 + jj * 16 + lrow] =
                            f2b(tanh_pre(fmaf(c1h[jj][mt][q], TK, bb)));
                }
        }
        __syncthreads();                  // epi visible; p==1: all H0A reads done
        if (p == 1) {                     // zero GTS pad cells (H0A dead)
            bhalf8 z = {0, 0, 0, 0, 0, 0, 0, 0};
            if (tid < 128)       *(bhalf8*)&smem[U_GTS + tid * GTSs + 32] = z;
            else if (tid == 128) *(bhalf8*)&smem[U_GTS + 5120] = z;
        }
        // L2 phase p over the compact half (real k = ks*64 + p*32 + lkg*8)
        #pragma unroll
        for (int ks = 0; ks < 4; ++ks) {
            bhalf8 a[3];
            #pragma unroll
            for (int mt = 0; mt < 3; ++mt) {
                int rr = mt * 16 + lrow;
                if (rr >= 34) rr = 32;   // clamp garbage rows in-bounds
                a[mt] = *(const bhalf8*)&smem[U_H1A + rr * H1S + ks * 32 + lkg * 8];
            }
            #pragma unroll
            for (int j2 = 0; j2 < 2; ++j2) {
                bhalf8 bf = *(const bhalf8*)(W2t + ((2 * wave + j2) * 16 + lrow) * 256
                                             + ks * 64 + p * 32 + lkg * 8);
                #pragma unroll
                for (int mt = 0; mt < 3; ++mt)
                    c2[j2][mt] = __builtin_amdgcn_mfma_f32_16x16x32_bf16(a[mt], bf, c2[j2][mt], 0, 0, 0);
            }
        }
        if (p == 0) __syncthreads();      // H1A-half reads done before p1 epi overwrite
    }

    // ---- L2 epilogue: g = exp(tanh(.)) -> GTS cells; k==0 -> gv regs ----
    float gv0[2] = {0.f, 0.f}, gv1[2] = {0.f, 0.f};
    {
        #pragma unroll
        for (int j = 0; j < 2; ++j) {
            const float bb = tb2[(2 * wave + j) * 16 + lrow] * TK;
            #pragma unroll
            for (int mt = 0; mt < 3; ++mt)
                #pragma unroll
                for (int q = 0; q < 4; ++q) {
                    int row = mt * 16 + lkg * 4 + q;
                    if (row < 34) {
                        int ml = (row >= 17);
                        int k = row - ml * 17;
                        int col = (2 * wave + j) * 16 + lrow;
                        float t = tanh_pre(fmaf(c2[j][mt][q], TK, bb));
                        float g = __builtin_amdgcn_exp2f(t * L2E);
                        if (k == 0) { if (ml) gv1[j] = g; else gv0[j] = g; }
                        else        smem[U_GTS + col * GTSs + ml * 16 + (k - 1)] = f2b(g);
                    }
                }
        }
    }
    __syncthreads();

    // ---- resvs (AS @ GTS -> AS2) + A2S build ----
    for (int idx = tid; idx < 512; idx += 256) {
        int r = idx >> 5, c = idx & 31;
        smem[U_A2S + idx] = ((c >> 4) == r) ? smem[U_AS + 16 * 32 + (c & 15)] : (ushort_t)0;
    }
    {
        bhalf8 a0 = *(const bhalf8*)&smem[U_AS + lrow * 32 + lkg * 8];
        bhalf8 a1 = *(const bhalf8*)&smem[U_AS + 16 * 32 + lkg * 8];  // uniform row 16
        for (int m = 0; m < 2; ++m) {
            #pragma unroll
            for (int j = 0; j < 2; ++j) {
                int nt = 2 * wave + j;
                bhalf8 bf = *(const bhalf8*)&smem[U_GTS + (nt * 16 + lrow) * GTSs + m * 16 + lkg * 8];
                #pragma unroll
                for (int mt = 0; mt < 2; ++mt) {
                    floatx4 c = {0.f, 0.f, 0.f, 0.f};
                    c = __builtin_amdgcn_mfma_f32_16x16x32_bf16(mt ? a1 : a0, bf, c, 0, 0, 0);
                    #pragma unroll
                    for (int q = 0; q < 4; ++q) {
                        int ic = mt * 16 + lkg * 4 + q;
                        if (ic < 17) {
                            int r2 = (ic == 16) ? m * 17 : m * 17 + 1 + ic;
                            smem[U_AS2 + r2 * AS2S + nt * 16 + lrow] = f2b(c[q]);
                        }
                    }
                }
            }
        }
    }
    __syncthreads();

    // ---- sw0: tanh(AS2@S0t+sb0) -> nv regs (i2==0) / GTS in-place ----
    float nv0[2] = {0.f, 0.f}, nv1[2] = {0.f, 0.f};
    {
        floatx4 c3[2][3];
        #pragma unroll
        for (int j = 0; j < 2; ++j)
            #pragma unroll
            for (int mt = 0; mt < 3; ++mt) c3[j][mt] = (floatx4){0.f, 0.f, 0.f, 0.f};
        #pragma unroll
        for (int ks = 0; ks < 4; ++ks) {
            bhalf8 a[3];
            #pragma unroll
            for (int mt = 0; mt < 3; ++mt) {
                int rr = mt * 16 + lrow;
                if (rr >= 34) rr = 32;       // clamp garbage rows in-bounds
                a[mt] = *(const bhalf8*)&smem[U_AS2 + rr * AS2S + ks * 32 + lkg * 8];
            }
            #pragma unroll
            for (int j = 0; j < 2; ++j) {
                bhalf8 bf = *(const bhalf8*)(S0t + ((2 * wave + j) * 16 + lrow) * 128 + ks * 32 + lkg * 8);
                #pragma unroll
                for (int mt = 0; mt < 3; ++mt)
                    c3[j][mt] = __builtin_amdgcn_mfma_f32_16x16x32_bf16(a[mt], bf, c3[j][mt], 0, 0, 0);
            }
        }
        #pragma unroll
        for (int j = 0; j < 2; ++j) {
            const float bb = sb0[(2 * wave + j) * 16 + lrow] * TK;
            #pragma unroll
            for (int mt = 0; mt < 3; ++mt)
                #pragma unroll
                for (int q = 0; q < 4; ++q) {
                    int r2 = mt * 16 + lkg * 4 + q;
                    if (r2 < 34) {
                        int m = (r2 >= 17);
                        int i2 = r2 - m * 17;
                        int col = (2 * wave + j) * 16 + lrow;
                        float val = tanh_pre(fmaf(c3[j][mt][q], TK, bb));
                        if (i2 == 0) {
                            if (m) nv1[j] = gv1[j] + val; else nv0[j] = gv0[j] + val;
                        } else {
                            int cell = U_GTS + col * GTSs + m * 16 + (i2 - 1);
                            smem[cell] = f2b(b2f(smem[cell]) + val);
                        }
                    }
                }
        }
    }
    __syncthreads();

    // ---- resv2: A2S @ GTS(updated) -> A3 (aliases dead AS2 head) ----
    {
        bhalf8 a = *(const bhalf8*)&smem[U_A2S + lrow * 32 + lkg * 8];
        #pragma unroll
        for (int j = 0; j < 2; ++j) {
            int nt = 2 * wave + j;
            bhalf8 bf = *(const bhalf8*)&smem[U_GTS + (nt * 16 + lrow) * GTSs + lkg * 8];
            floatx4 c = {0.f, 0.f, 0.f, 0.f};
            c = __builtin_amdgcn_mfma_f32_16x16x32_bf16(a, bf, c, 0, 0, 0);
            #pragma unroll
            for (int q = 0; q < 4; ++q) {
                int r = lkg * 4 + q;
                smem[U_A3 + r * AS2S + nt * 16 + lrow] = f2b(c[q]);
            }
        }
    }
    __syncthreads();

    // ---- green + output ----
    float acc = 0.0f;
    {
        bhalf8 a[4];
        #pragma unroll
        for (int ks = 0; ks < 4; ++ks)
            a[ks] = *(const bhalf8*)&smem[U_A3 + lrow * AS2S + ks * 32 + lkg * 8];
        #pragma unroll
        for (int j = 0; j < 2; ++j) {
            int nt = 2 * wave + j;
            float s1v = sb1[nt * 16 + lrow] * TK;
            float owv = outw[nt * 16 + lrow];
            floatx4 c = {0.f, 0.f, 0.f, 0.f};
            #pragma unroll
            for (int ks = 0; ks < 4; ++ks) {
                bhalf8 bf = *(const bhalf8*)(S1t + (nt * 16 + lrow) * 128 + ks * 32 + lkg * 8);
                c = __builtin_amdgcn_mfma_f32_16x16x32_bf16(a[ks], bf, c, 0, 0, 0);
            }
            if (lkg == 0) {
                #pragma unroll
                for (int q = 0; q < 2; ++q) {
                    float green = (q ? nv1[j] : nv0[j]) + tanh_pre(fmaf(c[q], TK, s1v));
                    acc += green * owv * smf[F_BBW + q];
                }
            }
        }
    }
    for (int o = 32; o > 0; o >>= 1) acc += __shfl_xor(acc, o, 64);
    if (lane == 0) smf[F_RED + wave] = acc;
    __syncthreads();
    if (tid == 0) {
        float tot = smf[F_RED + 0] + smf[F_RED + 1] + smf[F_RED + 2] + smf[F_RED + 3];
        atomicAdd(&out[bn], tot);
    }
}

extern "C" void kernel_launch(void* const* d_in, const int* in_sizes, int n_in,
                              void* d_out, int out_size, void* d_ws, size_t ws_size,
                              hipStream_t stream) {
    const float* phase    = (const float*)d_in[0];
    const float* bcoord   = (const float*)d_in[1];
    const float* boundary = (const float*)d_in[2];
    const float* bweights = (const float*)d_in[3];
    const float* posc     = (const float*)d_in[4];
    const float* sigma    = (const float*)d_in[5];
    const float* velc     = (const float*)d_in[6];
    const float* vweights = (const float*)d_in[7];
    const float* scat     = (const float*)d_in[8];
    const float* selfscat = (const float*)d_in[9];
    const float* aw0 = (const float*)d_in[10];
    const float* ab0 = (const float*)d_in[11];
    const float* aw1 = (const float*)d_in[12];
    const float* ab1 = (const float*)d_in[13];
    const float* aw2 = (const float*)d_in[14];
    const float* ab2 = (const float*)d_in[15];
    const float* tw0 = (const float*)d_in[16];
    const float* tb0 = (const float*)d_in[17];
    const float* tw1 = (const float*)d_in[18];
    const float* tb1 = (const float*)d_in[19];
    const float* tw2 = (const float*)d_in[20];
    const float* tb2 = (const float*)d_in[21];
    const float* sw0 = (const float*)d_in[22];
    const float* sb0 = (const float*)d_in[23];
    const float* sw1 = (const float*)d_in[24];
    const float* sb1 = (const float*)d_in[25];
    const float* outw = (const float*)d_in[26];

    float* out = (float*)d_out;
    char* ws = (char*)d_ws;
    ushort_t* W1t  = (ushort_t*)(ws + 0);         // 131072 B
    ushort_t* W2t  = (ushort_t*)(ws + 131072);    // 65536 B
    ushort_t* S0t  = (ushort_t*)(ws + 196608);    // 32768 B
    ushort_t* S1t  = (ushort_t*)(ws + 229376);    // 32768 B
    ushort_t* W0a  = (ushort_t*)(ws + 262144);    // 4096 B
    ushort_t* W1a  = (ushort_t*)(ws + 266240);    // 8192 B
    ushort_t* u_ws = (ushort_t*)(ws + 274432);    // 2176*256*2 = 1114112 B
    ushort_t* w_ws = (ushort_t*)(ws + 1388544);   // 256*256*2 = 131072 B -> 1519616 total

    hipMemsetAsync(d_out, 0, (size_t)out_size * sizeof(float), stream);

    prep_kernel<<<24, 256, 0, stream>>>(aw0, aw1, W0a, W1a);

    attn_kernel<<<BB * NN * KK1, 128, 0, stream>>>(
        phase, posc, sigma, velc, W0a, W1a, ab0, ab1, aw2, ab2, tw0, u_ws,
        tw1, tw2, sw0, sw1, tb0, bcoord, W1t, W2t, S0t, S1t, w_ws);

    transport_kernel<<<BB * NN * 32, 256, 0, stream>>>(
        boundary, bweights, vweights, scat, selfscat,
        W1t, W2t, S0t, S1t, tb1, tb2, sb0, sb1, outw, u_ws, w_ws, out);
}

// Round 15
// 261.493 us; speedup vs baseline: 1.0149x; 1.0149x over previous
//
#include <hip/hip_runtime.h>
#include <hip/hip_bf16.h>

#define BB 4
#define NN 32
#define MM 64
#define KK 16
#define KK1 17
#define PP 128
#define CC 2

typedef unsigned short ushort_t;
typedef unsigned int uint32;
typedef __attribute__((ext_vector_type(8))) short bhalf8;
typedef __attribute__((ext_vector_type(4))) float floatx4;

#define TK  2.885390082f   // 2*log2(e): tanh(x) = 1 - 2/(exp2(x*TK)+1)
#define L2E 1.44269504f

// 5-inst tanh: mul/fma upstream, v_exp, v_add, v_rcp, v_fma.
__device__ __forceinline__ float tanh_pre(float xs) {   // xs = x*TK already
    float e = __builtin_amdgcn_exp2f(xs);
    return fmaf(-2.0f, __builtin_amdgcn_rcpf(e + 1.0f), 1.0f);
}

__device__ __forceinline__ ushort_t f2b(float f) {
    uint32 u = __float_as_uint(f);
    return (ushort_t)((u + 0x8000u) >> 16);
}
__device__ __forceinline__ float b2f(ushort_t h) {
    return __uint_as_float(((uint32)h) << 16);
}

// u,w are PRE-SCALED by TK at generation (attn u-emit / prep w_ws)
__device__ __forceinline__ bhalf8 tanh_uw(bhalf8 u, bhalf8 w) {
    bhalf8 h;
    #pragma unroll
    for (int j = 0; j < 8; ++j)
        h[j] = (short)f2b(tanh_pre(b2f((ushort_t)u[j]) + b2f((ushort_t)w[j])));
    return h;
}

// ---------------------------------------------------------------------------
// Prep: weights -> bf16 B-operand layouts + w_ws[b*64+m][256] = xp,vp part of
// L0 pre-activation with tb0 folded in, PRE-SCALED by TK (bf16).
// ---------------------------------------------------------------------------
__global__ void prep_kernel(const float* __restrict__ tw0, const float* __restrict__ tw1,
                            const float* __restrict__ tw2, const float* __restrict__ sw0,
                            const float* __restrict__ sw1, const float* __restrict__ aw0,
                            const float* __restrict__ aw1, const float* __restrict__ tb0,
                            const float* __restrict__ bcoord,
                            ushort_t* __restrict__ W1t, ushort_t* __restrict__ W2t,
                            ushort_t* __restrict__ S0t, ushort_t* __restrict__ S1t,
                            ushort_t* __restrict__ W0a, ushort_t* __restrict__ W1a,
                            ushort_t* __restrict__ w_ws) {
    int i = blockIdx.x * 256 + threadIdx.x;
    if (i < 65536) {
        int nn = i >> 8, k = i & 255;
        W1t[i] = f2b(tw1[k * 256 + nn]);
    } else if (i < 98304) {
        int j = i - 65536; int nn = j >> 8, k = j & 255;
        W2t[j] = f2b(tw2[k * 128 + nn]);
    } else if (i < 114688) {
        S0t[i - 98304] = f2b(sw0[i - 98304]);
    } else if (i < 131072) {
        S1t[i - 114688] = f2b(sw1[i - 114688]);
    } else if (i < 133120) {
        int j = i - 131072; int nn = j >> 5, k = j & 31;
        W0a[j] = (k < 6) ? f2b(aw0[k * 64 + nn]) : (ushort_t)0;
    } else if (i < 137216) {
        int j = i - 133120; int nn = j >> 6, k = j & 63;
        W1a[j] = f2b(aw1[k * 64 + nn]);
    } else if (i < 202752) {
        int j = i - 137216;
        int m = j >> 8, c = j & 255;   // m = b*64 + mm
        float v = bcoord[m * 4 + 0] * tw0[4 * 256 + c]
                + bcoord[m * 4 + 1] * tw0[5 * 256 + c]
                + bcoord[m * 4 + 2] * tw0[6 * 256 + c]
                + bcoord[m * 4 + 3] * tw0[7 * 256 + c]
                + tb0[c];
        w_ws[j] = f2b(v * TK);
    }
}

// ---------------------------------------------------------------------------
// Kernel A (MFMA attn): R4 128-thr/2-wave structure + merged 2-round softmax.
// sH0 ALIASES sA0. LDS 19.5 KB -> 8 blocks/CU. Emits u_ws (PRE-SCALED by TK).
// ---------------------------------------------------------------------------
#define AH0S 72

__global__ __launch_bounds__(128, 4) void attn_kernel(
    const float* __restrict__ phase, const float* __restrict__ posc,
    const float* __restrict__ sigma, const float* __restrict__ velc,
    const ushort_t* __restrict__ W0a, const ushort_t* __restrict__ W1a,
    const float* __restrict__ ab0, const float* __restrict__ ab1,
    const float* __restrict__ aw2, const float* __restrict__ ab2,
    const float* __restrict__ tw0, ushort_t* __restrict__ u_ws)
{
    __shared__ __align__(16) ushort_t sAH[128 * AH0S];
    __shared__ float sPL[128];
    __shared__ float sLG[128];
    __shared__ float s_red[8];

    const int tid = threadIdx.x;
    const int wave = tid >> 6;
    const int lane = tid & 63;
    const int lrow = lane & 15;
    const int lkg  = lane >> 4;

    const int blk = blockIdx.x;
    const int b = blk / (NN * KK1);
    const int rem = blk % (NN * KK1);
    const int n = rem / KK1;
    const int k = rem % KK1;

    float x0, x1, va0, va1;
    {
        const int p = tid;
        x0 = phase[(b * NN + n) * 4 + 0];
        x1 = phase[(b * NN + n) * 4 + 1];
        if (k == 0) { va0 = phase[(b * NN + n) * 4 + 2]; va1 = phase[(b * NN + n) * 4 + 3]; }
        else { va0 = velc[(b * KK + (k - 1)) * 2 + 0]; va1 = velc[(b * KK + (k - 1)) * 2 + 1]; }
        const float inv = rsqrtf(va0 * va0 + va1 * va1 + 1e-16f);
        const float ag0 = va0 * inv, ag1 = va1 * inv;
        const float px = posc[(b * PP + p) * 2 + 0];
        const float py = posc[(b * PP + p) * 2 + 1];
        const float r0 = x0 - px, r1 = x1 - py;
        const float rd = sqrtf(r0 * r0 + r1 * r1 + 1e-16f);
        const float pl = r0 * ag0 + r1 * ag1;
        const float al = pl * __builtin_amdgcn_rcpf(rd + 1e-8f);
        sPL[p] = pl;
        bhalf8 f0;
        f0[0] = (short)f2b(x0); f0[1] = (short)f2b(x1);
        f0[2] = (short)f2b(va0); f0[3] = (short)f2b(va1);
        f0[4] = (short)f2b(al); f0[5] = (short)f2b(pl);
        f0[6] = 0; f0[7] = 0;
        bhalf8 z = {0, 0, 0, 0, 0, 0, 0, 0};
        *(bhalf8*)&sAH[p * 32 + 0] = f0;
        *(bhalf8*)&sAH[p * 32 + 8] = z;   // zero pad cols (NaN-safe 0*A)
        *(bhalf8*)&sAH[p * 32 + 16] = z;
        *(bhalf8*)&sAH[p * 32 + 24] = z;
    }
    __syncthreads();

    // ---- L1: h0 = tanh(A0 @ W0a + ab0) -> sH0 (aliases sA0) ----
    {
        float b0v[4];
        #pragma unroll
        for (int j = 0; j < 4; ++j) b0v[j] = ab0[j * 16 + lrow] * TK;
        bhalf8 a[4];
        #pragma unroll
        for (int mtl = 0; mtl < 4; ++mtl)
            a[mtl] = *(const bhalf8*)&sAH[(wave * 64 + mtl * 16 + lrow) * 32 + lkg * 8];
        __syncthreads();   // all waves hold A-frags in regs; sA0 region now dead
        #pragma unroll
        for (int j = 0; j < 4; ++j) {
            bhalf8 bf = *(const bhalf8*)(W0a + (j * 16 + lrow) * 32 + lkg * 8);
            #pragma unroll
            for (int mtl = 0; mtl < 4; ++mtl) {
                floatx4 c = {0.f, 0.f, 0.f, 0.f};
                c = __builtin_amdgcn_mfma_f32_16x16x32_bf16(a[mtl], bf, c, 0, 0, 0);
                #pragma unroll
                for (int q = 0; q < 4; ++q) {
                    int row = wave * 64 + mtl * 16 + lkg * 4 + q;
                    sAH[row * AH0S + j * 16 + lrow] = f2b(tanh_pre(fmaf(c[q], TK, b0v[j])));
                }
            }
        }
    }
    __syncthreads();

    // ---- L2 + logit ----
    {
        float b1v[4], w2v[4];
        #pragma unroll
        for (int j = 0; j < 4; ++j) { b1v[j] = ab1[j * 16 + lrow] * TK; w2v[j] = aw2[j * 16 + lrow]; }
        bhalf8 a0[4], a1[4];
        #pragma unroll
        for (int mtl = 0; mtl < 4; ++mtl) {
            int base = (wave * 64 + mtl * 16 + lrow) * AH0S;
            a0[mtl] = *(const bhalf8*)&sAH[base + lkg * 8];
            a1[mtl] = *(const bhalf8*)&sAH[base + 32 + lkg * 8];
        }
        float s[4][4];
        #pragma unroll
        for (int mtl = 0; mtl < 4; ++mtl)
            #pragma unroll
            for (int q = 0; q < 4; ++q) s[mtl][q] = 0.0f;
        #pragma unroll
        for (int j = 0; j < 4; ++j) {
            bhalf8 bf0 = *(const bhalf8*)(W1a + (j * 16 + lrow) * 64 + lkg * 8);
            bhalf8 bf1 = *(const bhalf8*)(W1a + (j * 16 + lrow) * 64 + 32 + lkg * 8);
            #pragma unroll
            for (int mtl = 0; mtl < 4; ++mtl) {
                floatx4 c = {0.f, 0.f, 0.f, 0.f};
                c = __builtin_amdgcn_mfma_f32_16x16x32_bf16(a0[mtl], bf0, c, 0, 0, 0);
                c = __builtin_amdgcn_mfma_f32_16x16x32_bf16(a1[mtl], bf1, c, 0, 0, 0);
                #pragma unroll
                for (int q = 0; q < 4; ++q)
                    s[mtl][q] += tanh_pre(fmaf(c[q], TK, b1v[j])) * w2v[j];
            }
        }
        #pragma unroll
        for (int mask = 1; mask <= 8; mask <<= 1)
            #pragma unroll
            for (int mtl = 0; mtl < 4; ++mtl)
                #pragma unroll
                for (int q = 0; q < 4; ++q)
                    s[mtl][q] += __shfl_xor(s[mtl][q], mask, 64);
        if (lrow == 0) {
            #pragma unroll
            for (int mtl = 0; mtl < 4; ++mtl)
                #pragma unroll
                for (int q = 0; q < 4; ++q)
                    sLG[wave * 64 + mtl * 16 + lkg * 4 + q] = s[mtl][q];
        }
    }
    __syncthreads();

    // ---- softmax (2 rounds, merged sv/s0/s1) + coeff -> u emit ----
    {
        const int p = tid;
        const float ml = (sPL[p] > 0.0f) ? (sLG[p] + ab2[0]) : -1e30f;
        const int wid = wave;
        float mv = ml;
        for (int o = 32; o > 0; o >>= 1) mv = fmaxf(mv, __shfl_xor(mv, o, 64));
        if (lane == 0) s_red[wid] = mv;
        __syncthreads();
        mv = fmaxf(s_red[0], s_red[1]);

        const float ew = __expf(ml - mv);
        float sv = ew;
        float s0 = ew * sigma[(b * PP + p) * 2 + 0];
        float s1 = ew * sigma[(b * PP + p) * 2 + 1];
        for (int o = 32; o > 0; o >>= 1) {
            sv += __shfl_xor(sv, o, 64);
            s0 += __shfl_xor(s0, o, 64);
            s1 += __shfl_xor(s1, o, 64);
        }
        if (lane == 0) { s_red[2 + wid] = sv; s_red[4 + wid] = s0; s_red[6 + wid] = s1; }
        __syncthreads();

        const float rsv = __builtin_amdgcn_rcpf(s_red[2] + s_red[3]);
        const float cc0 = __expf(-(s_red[4] + s_red[5]) * rsv);
        const float cc1 = __expf(-(s_red[6] + s_red[7]) * rsv);
        const float x0k = x0 * TK, x1k = x1 * TK;
        const float va0k = va0 * TK, va1k = va1 * TK;
        const float cc0k = cc0 * TK, cc1k = cc1 * TK;
        const int ubase = ((b * NN + n) * KK1 + k) * 256;
        for (int cc = tid; cc < 256; cc += 128) {
            float uv = x0k * tw0[cc] + x1k * tw0[256 + cc]
                     + va0k * tw0[512 + cc] + va1k * tw0[768 + cc]
                     + cc0k * tw0[2048 + cc] + cc1k * tw0[2304 + cc];
            u_ws[ubase + cc] = f2b(uv);
        }
    }
}

// ---------------------------------------------------------------------------
// Kernel B: MFMA transport. FINAL = byte-exact R10 (session best: 261.5 us
// total, transport 150-151 us). Closed levers (all measured): LDS footprint
// 40/32/28/22 KB (occupancy invariant at ~41%); launch_bounds(256,5) twice
// (spill tax > occupancy gain); accumulator restructures (gain was spill
// removal); bank conflicts (R12: counter -31%, time neutral -> off critical
// path); prep fusion (neutral). Structural constraint: barrier-serialized
// 9-phase dependent chain at register-capped 4 blocks/CU (unified VGPR+AGPR
// file); MfmaUtil 13% / VALUBusy 30% / HBM 0.6% -> latency regime.
//  - H0A FULL-K (34x264), filled once, ALL loads issued up-front.
//  - L1 col-halved: pass p computes col-tiles {2p,2p+1}, c1h[2][3]=24 accum.
//  - half-K compact H1A (34x136); W2t index ks*64 + p*32 + lkg*8.
//  - gv/nv in REGISTERS (writer thread == reader thread, lkg==0).
// Regions (u16 idx), lifetimes:
//   [0,8976)      H0A full (fill .. L1 pass1 reads; garbage rows to 12664)
//   [0,5128)      GTS (pads zeroed after H0A death; L2 epi .. resv2)
//   [5128,5640)   A2S (resvs .. resv2)
//   [8976,13600)  H1A half (pass epi .. L2 phase) -> AS2 (resvs .. sw0)
//                 -> A3 head (resv2 .. green)
//   [13600,14144) AS (start .. resvs)
//   floats: BBW u16 14144..14148, RED u16 14148..14156
// ---------------------------------------------------------------------------
#define H0S  264
#define H1S  136
#define GTSs 40
#define AS2S 136

#define U_H0A  0
#define U_GTS  0
#define U_A2S  5128
#define U_H1A  8976
#define U_AS2  8976
#define U_A3   8976
#define U_AS   13600
#define F_BBW  7072     // float idx -> u16 14144..14148
#define F_RED  7074     // float idx -> u16 14148..14156

__global__ __launch_bounds__(256, 4) void transport_kernel(
    const float* __restrict__ boundary, const float* __restrict__ bweights,
    const float* __restrict__ vweights, const float* __restrict__ scat,
    const float* __restrict__ selfscat,
    const ushort_t* __restrict__ W1t, const ushort_t* __restrict__ W2t,
    const ushort_t* __restrict__ S0t, const ushort_t* __restrict__ S1t,
    const float* __restrict__ tb1, const float* __restrict__ tb2,
    const float* __restrict__ sb0, const float* __restrict__ sb1,
    const float* __restrict__ outw,
    const ushort_t* __restrict__ u_ws, const ushort_t* __restrict__ w_ws,
    float* __restrict__ out)
{
    __shared__ __align__(16) ushort_t smem[14160];   // 28320 B
    float* smf = (float*)smem;

    const int tid = threadIdx.x;
    const int wave = tid >> 6;
    const int lane = tid & 63;
    const int lrow = lane & 15;
    const int lkg  = lane >> 4;

    const int blk = blockIdx.x;
    const int b  = blk >> 10;
    const int n  = (blk >> 5) & 31;
    const int mg = blk & 31;
    const int m0 = mg * 2;
    const int bn = b * NN + n;

    if (tid < 2)
        smf[F_BBW + tid] = boundary[b * MM + m0 + tid] * bweights[b * MM + m0 + tid];

    // ---- AS build ----
    for (int idx = tid; idx < 17 * 32; idx += 256) {
        int i = idx >> 5, c = idx & 31;
        float val = 0.0f;
        if (c < 16) {
            float vw = vweights[b * KK + c];
            val = (i < 16) ? (1.0f - selfscat[(b * KK + i) * KK + c]) * vw
                           : (1.0f - scat[bn * KK + c]) * vw;
        }
        smem[U_AS + idx] = f2b(val);
    }

    // ---- h0 fill, full-K, single phase. Loads issued up-front. ----
    {
        const int r0  = tid >> 5;        // 0..7
        const int oct = tid & 31;        // 0..31
        const int co  = oct * 8;
        const int rC  = 16 + r0;
        const int mlC = (rC >= 17) ? 1 : 0;
        const int kC  = rC - 17 * mlC;
        // only two distinct w rows (ml = 0/1): load once each
        const bhalf8 wml0 = *(const bhalf8*)(w_ws + (b * MM + m0 + 0) * 256 + co);
        const bhalf8 wml1 = *(const bhalf8*)(w_ws + (b * MM + m0 + 1) * 256 + co);
        const bhalf8 uA = *(const bhalf8*)(u_ws + (bn * KK1 + r0) * 256 + co);
        const bhalf8 uB = *(const bhalf8*)(u_ws + (bn * KK1 + 8 + r0) * 256 + co);
        const bhalf8 uC = *(const bhalf8*)(u_ws + (bn * KK1 + kC) * 256 + co);
        const bhalf8 uD = *(const bhalf8*)(u_ws + (bn * KK1 + 7 + r0) * 256 + co);
        bhalf8 uE;
        if (r0 < 2)
            uE = *(const bhalf8*)(u_ws + (bn * KK1 + 15 + r0) * 256 + co);
        *(bhalf8*)&smem[U_H0A + r0 * H0S + co]        = tanh_uw(uA, wml0);
        *(bhalf8*)&smem[U_H0A + (8 + r0) * H0S + co]  = tanh_uw(uB, wml0);
        *(bhalf8*)&smem[U_H0A + rC * H0S + co]        = tanh_uw(uC, mlC ? wml1 : wml0);
        *(bhalf8*)&smem[U_H0A + (24 + r0) * H0S + co] = tanh_uw(uD, wml1);
        if (r0 < 2)
            *(bhalf8*)&smem[U_H0A + (32 + r0) * H0S + co] = tanh_uw(uE, wml1);
    }
    __syncthreads();

    // ---- L1 col-half passes interleaved with L2 k-half phases ----
    floatx4 c2[2][3];
    #pragma unroll
    for (int j = 0; j < 2; ++j)
        #pragma unroll
        for (int mt = 0; mt < 3; ++mt) c2[j][mt] = (floatx4){0.f, 0.f, 0.f, 0.f};

    #pragma unroll
    for (int p = 0; p < 2; ++p) {
        // L1 pass p: cols {4*wave+2p, 4*wave+2p+1}, full K=256
        floatx4 c1h[2][3];
        #pragma unroll
        for (int j = 0; j < 2; ++j)
            #pragma unroll
            for (int mt = 0; mt < 3; ++mt) c1h[j][mt] = (floatx4){0.f, 0.f, 0.f, 0.f};
        #pragma unroll
        for (int ksl = 0; ksl < 8; ++ksl) {
            bhalf8 a[3];
            #pragma unroll
            for (int mt = 0; mt < 3; ++mt)
                a[mt] = *(const bhalf8*)&smem[U_H0A + (mt * 16 + lrow) * H0S + ksl * 32 + lkg * 8];
            #pragma unroll
            for (int jj = 0; jj < 2; ++jj) {
                bhalf8 bf = *(const bhalf8*)(W1t + ((4 * wave + 2 * p + jj) * 16 + lrow) * 256
                                             + ksl * 32 + lkg * 8);
                #pragma unroll
                for (int mt = 0; mt < 3; ++mt)
                    c1h[jj][mt] = __builtin_amdgcn_mfma_f32_16x16x32_bf16(a[mt], bf, c1h[jj][mt], 0, 0, 0);
            }
        }
        // epilogue -> compact H1A half (col = wave*32 + jj*16 + lrow)
        #pragma unroll
        for (int jj = 0; jj < 2; ++jj) {
            const float bb = tb1[(4 * wave + 2 * p + jj) * 16 + lrow] * TK;
            #pragma unroll
            for (int mt = 0; mt < 3; ++mt)
                #pragma unroll
                for (int q = 0; q < 4; ++q) {
                    const int row = mt * 16 + lkg * 4 + q;
                    if (row < 34)
                        smem[U_H1A + row * H1S + wave * 32 + jj * 16 + lrow] =
                            f2b(tanh_pre(fmaf(c1h[jj][mt][q], TK, bb)));
                }
        }
        __syncthreads();                  // epi visible; p==1: all H0A reads done
        if (p == 1) {                     // zero GTS pad cells (H0A dead)
            bhalf8 z = {0, 0, 0, 0, 0, 0, 0, 0};
            if (tid < 128)       *(bhalf8*)&smem[U_GTS + tid * GTSs + 32] = z;
            else if (tid == 128) *(bhalf8*)&smem[U_GTS + 5120] = z;
        }
        // L2 phase p over the compact half (real k = ks*64 + p*32 + lkg*8)
        #pragma unroll
        for (int ks = 0; ks < 4; ++ks) {
            bhalf8 a[3];
            #pragma unroll
            for (int mt = 0; mt < 3; ++mt) {
                int rr = mt * 16 + lrow;
                if (rr >= 34) rr = 32;   // clamp garbage rows in-bounds
                a[mt] = *(const bhalf8*)&smem[U_H1A + rr * H1S + ks * 32 + lkg * 8];
            }
            #pragma unroll
            for (int j2 = 0; j2 < 2; ++j2) {
                bhalf8 bf = *(const bhalf8*)(W2t + ((2 * wave + j2) * 16 + lrow) * 256
                                             + ks * 64 + p * 32 + lkg * 8);
                #pragma unroll
                for (int mt = 0; mt < 3; ++mt)
                    c2[j2][mt] = __builtin_amdgcn_mfma_f32_16x16x32_bf16(a[mt], bf, c2[j2][mt], 0, 0, 0);
            }
        }
        if (p == 0) __syncthreads();      // H1A-half reads done before p1 epi overwrite
    }

    // ---- L2 epilogue: g = exp(tanh(.)) -> GTS cells; k==0 -> gv regs ----
    float gv0[2] = {0.f, 0.f}, gv1[2] = {0.f, 0.f};
    {
        #pragma unroll
        for (int j = 0; j < 2; ++j) {
            const float bb = tb2[(2 * wave + j) * 16 + lrow] * TK;
            #pragma unroll
            for (int mt = 0; mt < 3; ++mt)
                #pragma unroll
                for (int q = 0; q < 4; ++q) {
                    int row = mt * 16 + lkg * 4 + q;
                    if (row < 34) {
                        int ml = (row >= 17);
                        int k = row - ml * 17;
                        int col = (2 * wave + j) * 16 + lrow;
                        float t = tanh_pre(fmaf(c2[j][mt][q], TK, bb));
                        float g = __builtin_amdgcn_exp2f(t * L2E);
                        if (k == 0) { if (ml) gv1[j] = g; else gv0[j] = g; }
                        else        smem[U_GTS + col * GTSs + ml * 16 + (k - 1)] = f2b(g);
                    }
                }
        }
    }
    __syncthreads();

    // ---- resvs (AS @ GTS -> AS2) + A2S build ----
    for (int idx = tid; idx < 512; idx += 256) {
        int r = idx >> 5, c = idx & 31;
        smem[U_A2S + idx] = ((c >> 4) == r) ? smem[U_AS + 16 * 32 + (c & 15)] : (ushort_t)0;
    }
    {
        bhalf8 a0 = *(const bhalf8*)&smem[U_AS + lrow * 32 + lkg * 8];
        bhalf8 a1 = *(const bhalf8*)&smem[U_AS + 16 * 32 + lkg * 8];  // uniform row 16
        for (int m = 0; m < 2; ++m) {
            #pragma unroll
            for (int j = 0; j < 2; ++j) {
                int nt = 2 * wave + j;
                bhalf8 bf = *(const bhalf8*)&smem[U_GTS + (nt * 16 + lrow) * GTSs + m * 16 + lkg * 8];
                #pragma unroll
                for (int mt = 0; mt < 2; ++mt) {
                    floatx4 c = {0.f, 0.f, 0.f, 0.f};
                    c = __builtin_amdgcn_mfma_f32_16x16x32_bf16(mt ? a1 : a0, bf, c, 0, 0, 0);
                    #pragma unroll
                    for (int q = 0; q < 4; ++q) {
                        int ic = mt * 16 + lkg * 4 + q;
                        if (ic < 17) {
                            int r2 = (ic == 16) ? m * 17 : m * 17 + 1 + ic;
                            smem[U_AS2 + r2 * AS2S + nt * 16 + lrow] = f2b(c[q]);
                        }
                    }
                }
            }
        }
    }
    __syncthreads();

    // ---- sw0: tanh(AS2@S0t+sb0) -> nv regs (i2==0) / GTS in-place ----
    float nv0[2] = {0.f, 0.f}, nv1[2] = {0.f, 0.f};
    {
        floatx4 c3[2][3];
        #pragma unroll
        for (int j = 0; j < 2; ++j)
            #pragma unroll
            for (int mt = 0; mt < 3; ++mt) c3[j][mt] = (floatx4){0.f, 0.f, 0.f, 0.f};
        #pragma unroll
        for (int ks = 0; ks < 4; ++ks) {
            bhalf8 a[3];
            #pragma unroll
            for (int mt = 0; mt < 3; ++mt) {
                int rr = mt * 16 + lrow;
                if (rr >= 34) rr = 32;       // clamp garbage rows in-bounds
                a[mt] = *(const bhalf8*)&smem[U_AS2 + rr * AS2S + ks * 32 + lkg * 8];
            }
            #pragma unroll
            for (int j = 0; j < 2; ++j) {
                bhalf8 bf = *(const bhalf8*)(S0t + ((2 * wave + j) * 16 + lrow) * 128 + ks * 32 + lkg * 8);
                #pragma unroll
                for (int mt = 0; mt < 3; ++mt)
                    c3[j][mt] = __builtin_amdgcn_mfma_f32_16x16x32_bf16(a[mt], bf, c3[j][mt], 0, 0, 0);
            }
        }
        #pragma unroll
        for (int j = 0; j < 2; ++j) {
            const float bb = sb0[(2 * wave + j) * 16 + lrow] * TK;
            #pragma unroll
            for (int mt = 0; mt < 3; ++mt)
                #pragma unroll
                for (int q = 0; q < 4; ++q) {
                    int r2 = mt * 16 + lkg * 4 + q;
                    if (r2 < 34) {
                        int m = (r2 >= 17);
                        int i2 = r2 - m * 17;
                        int col = (2 * wave + j) * 16 + lrow;
                        float val = tanh_pre(fmaf(c3[j][mt][q], TK, bb));
                        if (i2 == 0) {
                            if (m) nv1[j] = gv1[j] + val; else nv0[j] = gv0[j] + val;
                        } else {
                            int cell = U_GTS + col * GTSs + m * 16 + (i2 - 1);
                            smem[cell] = f2b(b2f(smem[cell]) + val);
                        }
                    }
                }
        }
    }
    __syncthreads();

    // ---- resv2: A2S @ GTS(updated) -> A3 (aliases dead AS2 head) ----
    {
        bhalf8 a = *(const bhalf8*)&smem[U_A2S + lrow * 32 + lkg * 8];
        #pragma unroll
        for (int j = 0; j < 2; ++j) {
            int nt = 2 * wave + j;
            bhalf8 bf = *(const bhalf8*)&smem[U_GTS + (nt * 16 + lrow) * GTSs + lkg * 8];
            floatx4 c = {0.f, 0.f, 0.f, 0.f};
            c = __builtin_amdgcn_mfma_f32_16x16x32_bf16(a, bf, c, 0, 0, 0);
            #pragma unroll
            for (int q = 0; q < 4; ++q) {
                int r = lkg * 4 + q;
                smem[U_A3 + r * AS2S + nt * 16 + lrow] = f2b(c[q]);
            }
        }
    }
    __syncthreads();

    // ---- green + output ----
    float acc = 0.0f;
    {
        bhalf8 a[4];
        #pragma unroll
        for (int ks = 0; ks < 4; ++ks)
            a[ks] = *(const bhalf8*)&smem[U_A3 + lrow * AS2S + ks * 32 + lkg * 8];
        #pragma unroll
        for (int j = 0; j < 2; ++j) {
            int nt = 2 * wave + j;
            float s1v = sb1[nt * 16 + lrow] * TK;
            float owv = outw[nt * 16 + lrow];
            floatx4 c = {0.f, 0.f, 0.f, 0.f};
            #pragma unroll
            for (int ks = 0; ks < 4; ++ks) {
                bhalf8 bf = *(const bhalf8*)(S1t + (nt * 16 + lrow) * 128 + ks * 32 + lkg * 8);
                c = __builtin_amdgcn_mfma_f32_16x16x32_bf16(a[ks], bf, c, 0, 0, 0);
            }
            if (lkg == 0) {
                #pragma unroll
                for (int q = 0; q < 2; ++q) {
                    float green = (q ? nv1[j] : nv0[j]) + tanh_pre(fmaf(c[q], TK, s1v));
                    acc += green * owv * smf[F_BBW + q];
                }
            }
        }
    }
    for (int o = 32; o > 0; o >>= 1) acc += __shfl_xor(acc, o, 64);
    if (lane == 0) smf[F_RED + wave] = acc;
    __syncthreads();
    if (tid == 0) {
        float tot = smf[F_RED + 0] + smf[F_RED + 1] + smf[F_RED + 2] + smf[F_RED + 3];
        atomicAdd(&out[bn], tot);
    }
}

extern "C" void kernel_launch(void* const* d_in, const int* in_sizes, int n_in,
                              void* d_out, int out_size, void* d_ws, size_t ws_size,
                              hipStream_t stream) {
    const float* phase    = (const float*)d_in[0];
    const float* bcoord   = (const float*)d_in[1];
    const float* boundary = (const float*)d_in[2];
    const float* bweights = (const float*)d_in[3];
    const float* posc     = (const float*)d_in[4];
    const float* sigma    = (const float*)d_in[5];
    const float* velc     = (const float*)d_in[6];
    const float* vweights = (const float*)d_in[7];
    const float* scat     = (const float*)d_in[8];
    const float* selfscat = (const float*)d_in[9];
    const float* aw0 = (const float*)d_in[10];
    const float* ab0 = (const float*)d_in[11];
    const float* aw1 = (const float*)d_in[12];
    const float* ab1 = (const float*)d_in[13];
    const float* aw2 = (const float*)d_in[14];
    const float* ab2 = (const float*)d_in[15];
    const float* tw0 = (const float*)d_in[16];
    const float* tb0 = (const float*)d_in[17];
    const float* tw1 = (const float*)d_in[18];
    const float* tb1 = (const float*)d_in[19];
    const float* tw2 = (const float*)d_in[20];
    const float* tb2 = (const float*)d_in[21];
    const float* sw0 = (const float*)d_in[22];
    const float* sb0 = (const float*)d_in[23];
    const float* sw1 = (const float*)d_in[24];
    const float* sb1 = (const float*)d_in[25];
    const float* outw = (const float*)d_in[26];

    float* out = (float*)d_out;
    char* ws = (char*)d_ws;
    ushort_t* W1t  = (ushort_t*)(ws + 0);         // 131072 B
    ushort_t* W2t  = (ushort_t*)(ws + 131072);    // 65536 B
    ushort_t* S0t  = (ushort_t*)(ws + 196608);    // 32768 B
    ushort_t* S1t  = (ushort_t*)(ws + 229376);    // 32768 B
    ushort_t* W0a  = (ushort_t*)(ws + 262144);    // 4096 B
    ushort_t* W1a  = (ushort_t*)(ws + 266240);    // 8192 B
    ushort_t* u_ws = (ushort_t*)(ws + 274432);    // 2176*256*2 = 1114112 B
    ushort_t* w_ws = (ushort_t*)(ws + 1388544);   // 256*256*2 = 131072 B -> 1519616 total

    hipMemsetAsync(d_out, 0, (size_t)out_size * sizeof(float), stream);

    prep_kernel<<<792, 256, 0, stream>>>(tw0, tw1, tw2, sw0, sw1, aw0, aw1, tb0, bcoord,
                                         W1t, W2t, S0t, S1t, W0a, W1a, w_ws);

    attn_kernel<<<BB * NN * KK1, 128, 0, stream>>>(
        phase, posc, sigma, velc, W0a, W1a, ab0, ab1, aw2, ab2, tw0, u_ws);

    transport_kernel<<<BB * NN * 32, 256, 0, stream>>>(
        boundary, bweights, vweights, scat, selfscat,
        W1t, W2t, S0t, S1t, tb1, tb2, sb0, sb1, outw, u_ws, w_ws, out);
}